// Round 2
// baseline (13202.847 us; speedup 1.0000x reference)
//
#include <hip/hip_runtime.h>
#include <hip/hip_bf16.h>
#include <cstdint>
#include <cstddef>

// Problem constants
#define VOCAB 32000
#define HID   1024
#define EMB   512
#define RANK  64
#define BATCH 16
#define SEQ   256
#define MROWS 4096      // SEQ*BATCH, row m = t*16 + b (time-major)
#define N1    1088      // HID + RANK
#define N1PAD 1152      // padded to 9*128

typedef __attribute__((ext_vector_type(8))) short short8;
typedef __attribute__((ext_vector_type(4))) float f32x4;

__device__ __forceinline__ float bf2f(unsigned short u) {
  unsigned int x = ((unsigned int)u) << 16;
  return __builtin_bit_cast(float, x);
}
__device__ __forceinline__ unsigned short f2bf(float f) {
  unsigned int x = __builtin_bit_cast(unsigned int, f);
  unsigned int r = (x + 0x7fffu + ((x >> 16) & 1u)) >> 16;
  return (unsigned short)r;
}
__device__ __forceinline__ void gl_lds16(const void* g, void* l) {
  __builtin_amdgcn_global_load_lds(
      (const __attribute__((address_space(1))) unsigned int*)g,
      (__attribute__((address_space(3))) unsigned int*)l, 16, 0, 0);
}

// ---------------------------------------------------------------------------
// prep: zero Hbuf[0], barrier counters, UBt pad rows (bf16)
// ---------------------------------------------------------------------------
__global__ void prep_misc(float* Hbuf0, unsigned int* bars, unsigned short* ubt_pad) {
  int i = blockIdx.x * blockDim.x + threadIdx.x;
  if (i < BATCH * HID) Hbuf0[i] = 0.f;
  if (i < 1024) bars[i] = 0u;
  if (i < 64 * EMB) ubt_pad[i] = 0;
}

// ---------------------------------------------------------------------------
// fp32 -> bf16 bulk convert (n multiple of 1024; each thread does 4)
// ---------------------------------------------------------------------------
__global__ void conv_f2b(const float* __restrict__ src, unsigned short* __restrict__ dst) {
  int i = (blockIdx.x * blockDim.x + threadIdx.x) * 4;
  float4 v = *(const float4*)(src + i);
  ushort4 o;
  o.x = f2bf(v.x); o.y = f2bf(v.y); o.z = f2bf(v.z); o.w = f2bf(v.w);
  *(ushort4*)(dst + i) = o;
}

// ---------------------------------------------------------------------------
// 32x32 tiled transpose + convert: src fp32 [R,C] -> dst bf16 [C,R]
// ---------------------------------------------------------------------------
__global__ void transpose_f2b(const float* __restrict__ src,
                              unsigned short* __restrict__ dst, int R, int C) {
  __shared__ float t[32][33];
  int c0 = blockIdx.x * 32, r0 = blockIdx.y * 32;
  int tx = threadIdx.x & 31, ty = threadIdx.x >> 5;  // 256 thr: ty 0..7
  for (int i = ty; i < 32; i += 8) t[i][tx] = src[(size_t)(r0 + i) * C + c0 + tx];
  __syncthreads();
  for (int i = ty; i < 32; i += 8)
    dst[(size_t)(c0 + i) * R + r0 + tx] = f2bf(t[tx][i]);
}

// ---------------------------------------------------------------------------
// MFMA GEMM: C = A[M,K] * Bt[N,K]^T (+bias fp32), 128x128 tile, BK=32.
// MODE 0: A rows gathered from emb_bf16 via tok; fp32 out, col<N guard,
//         bias only for col<HID.
// MODE 1: fp32 out to d_out with row remap (m=t*16+b -> orow=b*256+t)
// ---------------------------------------------------------------------------
template <int MODE>
__global__ __launch_bounds__(256) void gemm_bt(
    const unsigned short* __restrict__ Abase, const int* __restrict__ tok,
    const unsigned short* __restrict__ Bt, const float* __restrict__ bias,
    float* __restrict__ outf, int M, int N, int K, int ntiles) {
  __shared__ __align__(16) unsigned short As[128 * 32];
  __shared__ __align__(16) unsigned short Bs[128 * 32];
  int bn = blockIdx.x % ntiles, bm = blockIdx.x / ntiles;
  int tid = threadIdx.x, lane = tid & 63, w = tid >> 6;
  int wr = w >> 1, wc = w & 1;
  int fr = lane & 15, kq = lane >> 4;

  f32x4 zero = {0.f, 0.f, 0.f, 0.f};
  f32x4 acc[4][4];
#pragma unroll
  for (int i = 0; i < 4; ++i)
#pragma unroll
    for (int j = 0; j < 4; ++j) acc[i][j] = zero;

  int kIters = K >> 5;
  for (int kt = 0; kt < kIters; ++kt) {
    __syncthreads();
    int kb = kt << 5;
#pragma unroll
    for (int ii = 0; ii < 2; ++ii) {
      int e = w * 1024 + ii * 512 + lane * 8;  // element index in 128x32 tile
      int row = e >> 5, col = e & 31;
      {  // A tile
        int gm = bm * 128 + row;
        const unsigned short* gp;
        if (MODE == 0)
          gp = Abase + (size_t)tok[((gm & 15) << 8) + (gm >> 4)] * K + (kb + col);
        else
          gp = Abase + (size_t)gm * K + kb + col;
        gl_lds16(gp, &As[w * 1024 + ii * 512]);
      }
      {  // B tile (Bt is [N,K] row-major bf16)
        int gn = bn * 128 + row;
        const unsigned short* gp = Bt + (size_t)gn * K + kb + col;
        gl_lds16(gp, &Bs[w * 1024 + ii * 512]);
      }
    }
    __builtin_amdgcn_s_waitcnt(0);
    __syncthreads();

    short8 af[4], bfr[4];
#pragma unroll
    for (int mi = 0; mi < 4; ++mi)
      af[mi] = *(const short8*)&As[((wr << 6) + (mi << 4) + fr) * 32 + (kq << 3)];
#pragma unroll
    for (int ni = 0; ni < 4; ++ni)
      bfr[ni] = *(const short8*)&Bs[((wc << 6) + (ni << 4) + fr) * 32 + (kq << 3)];
#pragma unroll
    for (int mi = 0; mi < 4; ++mi)
#pragma unroll
      for (int ni = 0; ni < 4; ++ni)
        acc[mi][ni] = __builtin_amdgcn_mfma_f32_16x16x32_bf16(af[mi], bfr[ni],
                                                              acc[mi][ni], 0, 0, 0);
  }

  // epilogue: C/D layout col=lane&15, row=(lane>>4)*4+reg  [m89]
  int rbase = bm * 128 + (wr << 6);
  int cbase = bn * 128 + (wc << 6);
#pragma unroll
  for (int mi = 0; mi < 4; ++mi)
#pragma unroll
    for (int ni = 0; ni < 4; ++ni)
#pragma unroll
      for (int r = 0; r < 4; ++r) {
        int row = rbase + (mi << 4) + (kq << 2) + r;
        int col = cbase + (ni << 4) + fr;
        float v = acc[mi][ni][r];
        if (MODE == 0) {
          if (col < N) {
            float bv = (col < HID) ? bias[col] : 0.f;
            outf[(size_t)row * N + col] = v + bv;
          }
        } else {
          float o = v + bias[col];
          int orow = ((row & 15) << 8) + (row >> 4);  // b*256 + t
          outf[(size_t)orow * VOCAB + col] = o;
        }
      }
}

// ---------------------------------------------------------------------------
// Recurrent scan. 256 blocks x 256 threads. sample s = blk&15, part p = blk>>4.
// Block p owns h columns [64p,64p+64) and rank indices [4p,4p+4).
// V-slice (bf16) / A-share (bf16) / C-slice (bf16) cached in LDS once.
// Two per-sample device-scope barriers per step (monotonic counters).
// ---------------------------------------------------------------------------
__global__ __launch_bounds__(256) void scan_kernel(
    const float* __restrict__ u_cat,     // [4096][1088] fp32 = [xU+d | xB]
    const float* __restrict__ A,         // [1024][64] fp32
    const float* __restrict__ V,         // [1024][1024] fp32
    const float* __restrict__ Cm,        // [1024][64] fp32
    float* __restrict__ Hbuf,            // [2][16][1024] fp32
    float* __restrict__ a_buf,           // [16][64] fp32
    unsigned int* __restrict__ bars,     // monotonic counters
    unsigned short* __restrict__ hseq) { // [4096][1024] bf16
  __shared__ __align__(16) unsigned short Vt[64][1032];  // Vt[j][h]=V[h][64p+j]
  __shared__ __align__(16) float h_lds[1024];
  __shared__ __align__(16) unsigned short As2[4 * 1024]; // As2[rr][h]=A[h][4p+rr]
  __shared__ __align__(16) unsigned short Cs[64][66];    // Cs[j][r]=C[64p+j][r]
  __shared__ float zpart[64][4];
  __shared__ float cppart[64][4];

  const int s = blockIdx.x & 15, p = blockIdx.x >> 4;
  const int tid = threadIdx.x, lane = tid & 63, w = tid >> 6;

  // one-time LDS fills (fp32 global -> bf16 LDS)
  {
    const float* vp = V + (size_t)(w * 256) * HID + p * 64 + lane;
    for (int i = 0; i < 256; ++i) Vt[lane][w * 256 + i] = f2bf(vp[(size_t)i * HID]);
  }
  for (int idx = tid; idx < 4096; idx += 256) {
    int rr = idx >> 10, h = idx & 1023;
    As2[idx] = f2bf(A[h * RANK + p * 4 + rr]);
  }
  for (int idx = tid; idx < 4096; idx += 256) {
    int j = idx >> 6, r = idx & 63;
    Cs[j][r] = f2bf(Cm[(p * 64 + j) * RANK + r]);
  }
  __syncthreads();

  unsigned int* bar1 = bars + s * 32;
  unsigned int* bar2 = bars + 512 + s * 32;

  for (int t = 0; t < SEQ; ++t) {
    const int cur = t & 1, nxt = cur ^ 1;
    const float* hsrc = Hbuf + cur * (BATCH * HID) + s * HID;
    {  // load h -> LDS (agent-scope loads bypass L1: fresh cross-block data)
      int i0 = tid * 4;
#pragma unroll
      for (int k = 0; k < 4; ++k)
        h_lds[i0 + k] =
            __hip_atomic_load(hsrc + i0 + k, __ATOMIC_RELAXED, __HIP_MEMORY_SCOPE_AGENT);
    }
    __syncthreads();

    // a-part: wave w computes a[4p+w] = sum_h h[h]*A[h][4p+w]
    float ap = 0.f;
#pragma unroll
    for (int ii = 0; ii < 16; ++ii) {
      int h = ii * 64 + lane;
      ap += h_lds[h] * bf2f(As2[w * 1024 + h]);
    }
#pragma unroll
    for (int off = 32; off > 0; off >>= 1) ap += __shfl_down(ap, off);
    if (lane == 0)
      __hip_atomic_store(&a_buf[s * 64 + p * 4 + w], ap, __ATOMIC_RELAXED,
                         __HIP_MEMORY_SCOPE_AGENT);
    __syncthreads();  // all 4 waves' a stores drained (barrier waits vmcnt)
    if (tid == 0) {
      __threadfence();
      __hip_atomic_fetch_add(bar1, 1u, __ATOMIC_RELEASE, __HIP_MEMORY_SCOPE_AGENT);
    }

    // V matvec: thread (j=lane, q=w) sums h in [256w, 256w+256)
    float v0 = 0.f, v1 = 0.f;
    {
      const unsigned short* vrow = &Vt[lane][w * 256];
      const float* hp = &h_lds[w * 256];
#pragma unroll 4
      for (int i = 0; i < 256; i += 8) {
        uint4 vv = *(const uint4*)(vrow + i);
        float4 ha = *(const float4*)(hp + i);
        float4 hb = *(const float4*)(hp + i + 4);
        v0 += bf2f((unsigned short)(vv.x & 0xffffu)) * ha.x +
              bf2f((unsigned short)(vv.x >> 16)) * ha.y +
              bf2f((unsigned short)(vv.y & 0xffffu)) * ha.z +
              bf2f((unsigned short)(vv.y >> 16)) * ha.w;
        v1 += bf2f((unsigned short)(vv.z & 0xffffu)) * hb.x +
              bf2f((unsigned short)(vv.z >> 16)) * hb.y +
              bf2f((unsigned short)(vv.w & 0xffffu)) * hb.z +
              bf2f((unsigned short)(vv.w >> 16)) * hb.w;
      }
    }
    zpart[lane][w] = v0 + v1;

    // wait bar1 (a ready, all 16 blocks of this sample)
    {
      unsigned int tgt = (unsigned int)(t + 1) * 16u;
      while (__hip_atomic_load(bar1, __ATOMIC_ACQUIRE, __HIP_MEMORY_SCOPE_AGENT) < tgt)
        __builtin_amdgcn_s_sleep(1);
    }

    // cp partial: thread (j=lane) sums r in [16w,16w+16)
    float cpp = 0.f;
    {
      const float* abuf = a_buf + s * 64;
      const float* bb = u_cat + (size_t)(t * 16 + s) * N1 + HID;
#pragma unroll
      for (int rr = 0; rr < 16; ++rr) {
        int r = w * 16 + rr;
        float av = __hip_atomic_load(abuf + r, __ATOMIC_RELAXED, __HIP_MEMORY_SCOPE_AGENT);
        cpp += av * bb[r] * bf2f(Cs[lane][r]);
      }
    }
    cppart[lane][w] = cpp;
    __syncthreads();

    if (tid < 64) {
      int j = tid;
      float z = u_cat[(size_t)(t * 16 + s) * N1 + p * 64 + j];
      z += zpart[j][0] + zpart[j][1] + zpart[j][2] + zpart[j][3];
      z += cppart[j][0] + cppart[j][1] + cppart[j][2] + cppart[j][3];
      float hn = tanhf(z);
      __hip_atomic_store(&Hbuf[nxt * (BATCH * HID) + s * HID + p * 64 + j], hn,
                         __ATOMIC_RELAXED, __HIP_MEMORY_SCOPE_AGENT);
      hseq[(size_t)(t * 16 + s) * HID + p * 64 + j] = f2bf(hn);
    }
    __syncthreads();
    if (tid == 0) {
      __threadfence();
      __hip_atomic_fetch_add(bar2, 1u, __ATOMIC_RELEASE, __HIP_MEMORY_SCOPE_AGENT);
    }
    {
      unsigned int tgt = (unsigned int)(t + 1) * 16u;
      while (__hip_atomic_load(bar2, __ATOMIC_ACQUIRE, __HIP_MEMORY_SCOPE_AGENT) < tgt)
        __builtin_amdgcn_s_sleep(1);
    }
  }
}

// ---------------------------------------------------------------------------
extern "C" void kernel_launch(void* const* d_in, const int* in_sizes, int n_in,
                              void* d_out, int out_size, void* d_ws, size_t ws_size,
                              hipStream_t stream) {
  const int*   inp  = (const int*)d_in[0];
  const float* emb  = (const float*)d_in[1];   // [32000][512]
  const float* Amat = (const float*)d_in[2];   // [1024][64]
  const float* Bmat = (const float*)d_in[3];   // [512][64]
  const float* Cmat = (const float*)d_in[4];   // [1024][64]
  const float* Umat = (const float*)d_in[5];   // [512][1024]
  const float* Vmat = (const float*)d_in[6];   // [1024][1024]
  const float* dvec = (const float*)d_in[7];   // [1024]
  const float* Wdec = (const float*)d_in[8];   // [1024][32000]
  const float* bdec = (const float*)d_in[9];   // [32000]
  float* out = (float*)d_out;

  char* ws = (char*)d_ws;
  size_t off = 0;
  auto alloc = [&](size_t bytes) -> void* {
    void* pp = ws + off;
    off = (off + bytes + 255) & ~(size_t)255;
    return pp;
  };
  // persistent region
  unsigned short* hseq = (unsigned short*)alloc((size_t)MROWS * HID * 2);  // 8.39 MB
  float* Hbuf  = (float*)alloc((size_t)2 * BATCH * HID * 4);
  float* a_buf = (float*)alloc((size_t)BATCH * RANK * 4);
  unsigned int* bars = (unsigned int*)alloc(1024 * 4);
  // union region: {emb_bf16, UBt, u_cat} (phases 1-3) aliased with WdT (4-5)
  size_t union_off = off;
  unsigned short* emb_b = (unsigned short*)alloc((size_t)VOCAB * EMB * 2);  // 32.8 MB
  unsigned short* UBt   = (unsigned short*)alloc((size_t)N1PAD * EMB * 2);  // 1.18 MB
  float* u_cat = (float*)alloc((size_t)MROWS * N1 * 4);                     // 17.8 MB
  unsigned short* WdT = (unsigned short*)(ws + union_off);                  // 65.5 MB alias

  // phase 0: prep + conversions
  prep_misc<<<128, 256, 0, stream>>>(Hbuf, bars, UBt + (size_t)N1 * EMB);
  conv_f2b<<<(VOCAB * EMB) / 1024, 256, 0, stream>>>(emb, emb_b);
  // UBt rows 0..1023 = U^T, rows 1024..1087 = B^T, rows 1088..1151 = 0
  transpose_f2b<<<dim3(HID / 32, EMB / 32), 256, 0, stream>>>(Umat, UBt, EMB, HID);
  transpose_f2b<<<dim3(RANK / 32, EMB / 32), 256, 0, stream>>>(
      Bmat, UBt + (size_t)HID * EMB, EMB, RANK);

  // phase 1: u_cat = gather(embedding, inp) @ [U | B] + [d | 0]
  gemm_bt<0><<<9 * (MROWS / 128), 256, 0, stream>>>(emb_b, inp, UBt, dvec, u_cat,
                                                    MROWS, N1, EMB, 9);
  // phase 2: recurrent scan
  scan_kernel<<<256, 256, 0, stream>>>(u_cat, Amat, Vmat, Cmat, Hbuf, a_buf, bars, hseq);
  // phase 3: W_dec transpose (aliases dead emb_b/UBt/u_cat region)
  transpose_f2b<<<dim3(VOCAB / 32, HID / 32), 256, 0, stream>>>(Wdec, WdT, HID, VOCAB);
  // phase 4: logits = hseq @ W_dec + b_dec, remapped to [B,S,V]
  gemm_bt<1><<<250 * (MROWS / 128), 256, 0, stream>>>(hseq, nullptr, WdT, bdec, out,
                                                      MROWS, VOCAB, HID, 250);
}